// Round 1
// baseline (235.450 us; speedup 1.0000x reference)
//
#include <hip/hip_runtime.h>

#define N_  2
#define C_  256
#define CK_ 32
#define L_  4096

typedef __attribute__((ext_vector_type(8))) short short8;   // 8 bf16 (4 VGPRs)
typedef __attribute__((ext_vector_type(4))) float f32x4;    // MFMA C/D
typedef __attribute__((ext_vector_type(2))) unsigned int uint2v;
typedef unsigned short ushort;

__device__ __forceinline__ ushort f2bf(float f){
  unsigned u = __float_as_uint(f);
  u += 0x7fffu + ((u >> 16) & 1u);     // RNE
  return (ushort)(u >> 16);
}

__device__ __forceinline__ f32x4 mfma16(short8 a, short8 b, f32x4 c){
  return __builtin_amdgcn_mfma_f32_16x16x32_bf16(a, b, c, 0, 0, 0);
}

// ---------- convert+transpose x: [n][C][L] f32 -> [n][L][C] bf16 ----------
__global__ __launch_bounds__(256) void convert_x_kernel(
    const float* __restrict__ x1, const float* __restrict__ x2,
    ushort* __restrict__ xT1, ushort* __restrict__ xT2){
  __shared__ float tile[64][65];
  int z = blockIdx.z; int n = z & 1;
  const float* x = (z >> 1) ? x2 : x1;
  ushort* xT = (z >> 1) ? xT2 : xT1;
  int l0 = blockIdx.x * 64, c0 = blockIdx.y * 64;
  int t = threadIdx.x, li = t & 63, s4 = t >> 6;
  const float* xs = x + (size_t)n * C_ * L_;
  ushort* xd = xT + (size_t)n * L_ * C_;
#pragma unroll
  for (int r = 0; r < 16; ++r){ int cl = r*4 + s4; tile[cl][li] = xs[(size_t)(c0+cl)*L_ + l0 + li]; }
  __syncthreads();
#pragma unroll
  for (int r = 0; r < 16; ++r){ int ll = r*4 + s4; xd[(size_t)(l0+ll)*C_ + c0 + li] = f2bf(tile[li][ll]); }
}

// ---------- convert weights f32 -> bf16 (flat) ----------
__global__ __launch_bounds__(256) void convert_w_kernel(
    const float* __restrict__ Wk1, const float* __restrict__ Wk2,
    const float* __restrict__ Wv1, const float* __restrict__ Wv2,
    ushort* __restrict__ o1, ushort* __restrict__ o2,
    ushort* __restrict__ o3, ushort* __restrict__ o4){
  int idx = blockIdx.x * 256 + threadIdx.x;
  const int KS = CK_ * C_;      // 8192
  const int VS = C_ * C_;       // 65536
  if (idx < KS)                 o1[idx] = f2bf(Wk1[idx]);
  else if (idx < 2*KS)          o2[idx - KS] = f2bf(Wk2[idx - KS]);
  else if (idx < 2*KS + VS)     o3[idx - 2*KS] = f2bf(Wv1[idx - 2*KS]);
  else if (idx < 2*KS + 2*VS)   o4[idx - 2*KS - VS] = f2bf(Wv2[idx - 2*KS - VS]);
}

// ---------- fused projections: k1t/k2t [n][L][CK], v1/v2 [n][C][L] ----------
// out[j,l] = sum_c W[j,c]*x[c,l] + b[j].  A from Wbf [j][C], B from xT [l][C].
__global__ __launch_bounds__(256) void proj_kernel(
    const ushort* __restrict__ xT1, const ushort* __restrict__ xT2,
    const ushort* __restrict__ Wk1b, const ushort* __restrict__ Wk2b,
    const ushort* __restrict__ Wv1b, const ushort* __restrict__ Wv2b,
    const float* __restrict__ bk1, const float* __restrict__ bk2,
    const float* __restrict__ bv1, const float* __restrict__ bv2,
    ushort* __restrict__ k1t, ushort* __restrict__ k2t,
    ushort* __restrict__ v1,  ushort* __restrict__ v2){
  int y = blockIdx.y, n = blockIdx.z;
  int t = threadIdx.x, w = t >> 6, lane = t & 63, quad = lane >> 4, low = lane & 15;
  const ushort* X; const ushort* W; const float* bias; ushort* outp; int jt; bool isK;
  if (y < 8)       { X = xT1; W = Wv1b; bias = bv1; outp = v1;  jt = y;     isK = false; }
  else if (y < 16) { X = xT2; W = Wv2b; bias = bv2; outp = v2;  jt = y - 8; isK = false; }
  else if (y == 16){ X = xT1; W = Wk1b; bias = bk1; outp = k1t; jt = 0;     isK = true; }
  else             { X = xT2; W = Wk2b; bias = bk2; outp = k2t; jt = 0;     isK = true; }
  int j0 = jt * 32;
  int l0 = blockIdx.x * 128 + w * 32;
  const ushort* Xn = X + (size_t)n * L_ * C_;
  f32x4 acc[2][2] = {};
#pragma unroll
  for (int kc = 0; kc < 8; ++kc){
    short8 a[2], b[2];
#pragma unroll
    for (int js = 0; js < 2; ++js)
      a[js] = *(const short8*)(W + (size_t)(j0 + js*16 + low)*C_ + kc*32 + quad*8);
#pragma unroll
    for (int ls = 0; ls < 2; ++ls)
      b[ls] = *(const short8*)(Xn + (size_t)(l0 + ls*16 + low)*C_ + kc*32 + quad*8);
#pragma unroll
    for (int js = 0; js < 2; ++js)
#pragma unroll
      for (int ls = 0; ls < 2; ++ls)
        acc[js][ls] = mfma16(a[js], b[ls], acc[js][ls]);
  }
#pragma unroll
  for (int js = 0; js < 2; ++js){
    f32x4 bb = *(const f32x4*)(bias + j0 + js*16 + quad*4);
#pragma unroll
    for (int ls = 0; ls < 2; ++ls){
      int l = l0 + ls*16 + low;
      if (!isK){
#pragma unroll
        for (int r = 0; r < 4; ++r){
          int j = j0 + js*16 + quad*4 + r;
          outp[((size_t)n*C_ + j)*L_ + l] = f2bf(acc[js][ls][r] + bb[r]);
        }
      } else {
        union { ushort u[4]; uint2v v; } pk;
#pragma unroll
        for (int r = 0; r < 4; ++r) pk.u[r] = f2bf(acc[js][ls][r] + bb[r]);
        *(uint2v*)(outp + ((size_t)n*L_ + l)*CK_ + j0 + js*16 + quad*4) = pk.v;
      }
    }
  }
}

// ---------- stats: partial row/col sums of exp(cor) ----------
// cor[l,m] = sum_k k1t[l,k]*k2t[m,k]. S1part[n][mtile][l], S2part[n][ltile][m].
__global__ __launch_bounds__(256) void stats_kernel(
    const ushort* __restrict__ k1t, const ushort* __restrict__ k2t,
    float* __restrict__ S1part, float* __restrict__ S2part){
  int n = blockIdx.z;
  int m0 = blockIdx.x * 128, l0 = blockIdx.y * 128;
  int t = threadIdx.x, w = t >> 6, lane = t & 63, quad = lane >> 4, low = lane & 15;
  __shared__ float rowsum[128];
  __shared__ float colsum[4][128];
  const ushort* ka = k1t + (size_t)n * L_ * CK_;
  const ushort* kb = k2t + (size_t)n * L_ * CK_;
  short8 a[2], b[8];
#pragma unroll
  for (int lt = 0; lt < 2; ++lt)
    a[lt] = *(const short8*)(ka + (size_t)(l0 + w*32 + lt*16 + low)*CK_ + quad*8);
#pragma unroll
  for (int mt = 0; mt < 8; ++mt)
    b[mt] = *(const short8*)(kb + (size_t)(m0 + mt*16 + low)*CK_ + quad*8);
  float rp[2][4] = {}; float cp[8] = {};
  const f32x4 zero = {0.f, 0.f, 0.f, 0.f};
#pragma unroll
  for (int lt = 0; lt < 2; ++lt)
#pragma unroll
    for (int mt = 0; mt < 8; ++mt){
      f32x4 e = mfma16(a[lt], b[mt], zero);
#pragma unroll
      for (int r = 0; r < 4; ++r){
        float v = __expf(e[r]);
        rp[lt][r] += v;
        cp[mt] += v;
      }
    }
#pragma unroll
  for (int lt = 0; lt < 2; ++lt)
#pragma unroll
    for (int r = 0; r < 4; ++r){
      float v = rp[lt][r];
      v += __shfl_xor(v, 1); v += __shfl_xor(v, 2);
      v += __shfl_xor(v, 4); v += __shfl_xor(v, 8);
      if (low == 0) rowsum[w*32 + lt*16 + quad*4 + r] = v;
    }
#pragma unroll
  for (int mt = 0; mt < 8; ++mt){
    float v = cp[mt];
    v += __shfl_xor(v, 16); v += __shfl_xor(v, 32);
    if (quad == 0) colsum[w][mt*16 + low] = v;
  }
  __syncthreads();
  if (t < 128)
    S1part[((size_t)n*32 + blockIdx.x)*L_ + l0 + t] = rowsum[t];
  else {
    int m = t - 128;
    S2part[((size_t)n*32 + blockIdx.y)*L_ + m0 + m] =
        colsum[0][m] + colsum[1][m] + colsum[2][m] + colsum[3][m];
  }
}

// ---------- reduce partials -> 1/S ----------
__global__ __launch_bounds__(256) void reduce_inv_kernel(
    const float* __restrict__ S1part, const float* __restrict__ S2part,
    float* __restrict__ invS1, float* __restrict__ invS2){
  int idx = blockIdx.x * 256 + threadIdx.x;          // 0..16383
  int which = idx >> 13;
  int r = idx & 8191;                                // n*L + l
  int n = r >> 12, l = r & 4095;
  const float* P = which ? S2part : S1part;
  float s = 0.f;
#pragma unroll
  for (int j = 0; j < 32; ++j) s += P[((size_t)n*32 + j)*L_ + l];
  (which ? invS2 : invS1)[(size_t)n*L_ + l] = 1.0f / s;
}

// ---------- unified flash r-kernel ----------
// out[c,q] = x[c,q] + sum_p v[c,p] * exp(sum_k kA[p,k]*kB[q,k]) * invS[p]
// grid (L/64, C/128, 4): z = which*2 + n. Tile: 128c x 64q, K-chunk BP=128.
__global__ __launch_bounds__(256, 2) void cross_attn_r_kernel(
    const ushort* __restrict__ k1t, const ushort* __restrict__ k2t,
    const ushort* __restrict__ v1,  const ushort* __restrict__ v2,
    const float* __restrict__ invS1, const float* __restrict__ invS2,
    const float* __restrict__ x1, const float* __restrict__ x2,
    float* __restrict__ out){
  int z = blockIdx.z; int which = z >> 1; int n = z & 1;
  const ushort* kA = which ? k2t : k1t;
  const ushort* kB = which ? k1t : k2t;
  const ushort* V  = which ? v2  : v1;
  const float* iS  = which ? invS2 : invS1;
  const float* X   = which ? x2 : x1;
  float* O = out + (size_t)which * N_ * C_ * L_;
  int q0 = blockIdx.x * 64, c0 = blockIdx.y * 128;
  int t = threadIdx.x, w = t >> 6, lane = t & 63, quad = lane >> 4, low = lane & 15;
  __shared__ __align__(16) ushort ptile[64][136];   // [q][p], 272B rows (16B aligned)
  const ushort* kAn = kA + (size_t)n * L_ * CK_;
  const ushort* kBn = kB + (size_t)n * L_ * CK_;
  const ushort* Vn  = V  + (size_t)n * C_ * L_;
  const float*  iSn = iS + (size_t)n * L_;
  // E-phase B operands are p-invariant: preload once.
  short8 be[4];
#pragma unroll
  for (int qs = 0; qs < 4; ++qs)
    be[qs] = *(const short8*)(kBn + (size_t)(q0 + qs*16 + low)*CK_ + quad*8);
  f32x4 acc[2][4] = {};
  const f32x4 zero = {0.f, 0.f, 0.f, 0.f};
  for (int p0 = 0; p0 < L_; p0 += 128){
    // --- E phase: compute P chunk [128p x 64q] -> LDS transposed [q][p] bf16
#pragma unroll
    for (int ps = 0; ps < 2; ++ps){
      short8 a = *(const short8*)(kAn + (size_t)(p0 + w*32 + ps*16 + low)*CK_ + quad*8);
      f32x4 sv = *(const f32x4*)(iSn + p0 + w*32 + ps*16 + quad*4);
#pragma unroll
      for (int qs = 0; qs < 4; ++qs){
        f32x4 e = mfma16(a, be[qs], zero);
        union { ushort u[4]; uint2v v; } pk;
#pragma unroll
        for (int r = 0; r < 4; ++r) pk.u[r] = f2bf(__expf(e[r]) * sv[r]);
        *(uint2v*)&ptile[qs*16 + low][w*32 + ps*16 + quad*4] = pk.v;
      }
    }
    __syncthreads();
    // --- main phase: acc[c,q] += V[c,p] * P[p,q]
#pragma unroll
    for (int ks = 0; ks < 4; ++ks){
      short8 bb[4];
#pragma unroll
      for (int qs = 0; qs < 4; ++qs)
        bb[qs] = *(const short8*)&ptile[qs*16 + low][ks*32 + quad*8];
#pragma unroll
      for (int cs = 0; cs < 2; ++cs){
        short8 a = *(const short8*)(Vn + (size_t)(c0 + w*32 + cs*16 + low)*L_ + p0 + ks*32 + quad*8);
#pragma unroll
        for (int qs = 0; qs < 4; ++qs)
          acc[cs][qs] = mfma16(a, bb[qs], acc[cs][qs]);
      }
    }
    __syncthreads();
  }
  // --- epilogue: out = x + acc
#pragma unroll
  for (int cs = 0; cs < 2; ++cs)
#pragma unroll
    for (int qs = 0; qs < 4; ++qs){
      int q = q0 + qs*16 + low;
      int cbase = c0 + w*32 + cs*16 + quad*4;
#pragma unroll
      for (int r = 0; r < 4; ++r){
        size_t idx = ((size_t)n*C_ + cbase + r)*L_ + q;
        O[idx] = X[idx] + acc[cs][qs][r];
      }
    }
}

extern "C" void kernel_launch(void* const* d_in, const int* in_sizes, int n_in,
                              void* d_out, int out_size, void* d_ws, size_t ws_size,
                              hipStream_t stream) {
  const float* x1  = (const float*)d_in[0];
  const float* x2  = (const float*)d_in[1];
  const float* Wk1 = (const float*)d_in[2];
  const float* bk1 = (const float*)d_in[3];
  const float* Wk2 = (const float*)d_in[4];
  const float* bk2 = (const float*)d_in[5];
  const float* Wv1 = (const float*)d_in[6];
  const float* bv1 = (const float*)d_in[7];
  const float* Wv2 = (const float*)d_in[8];
  const float* bv2 = (const float*)d_in[9];

  char* ws = (char*)d_ws;
  size_t off = 0;
  auto carve = [&](size_t bytes) -> void* {
    void* p = ws + off; off += (bytes + 255) & ~(size_t)255; return p;
  };
  ushort* xT1   = (ushort*)carve((size_t)N_*L_*C_*2);
  ushort* xT2   = (ushort*)carve((size_t)N_*L_*C_*2);
  ushort* Wk1b  = (ushort*)carve((size_t)CK_*C_*2);
  ushort* Wk2b  = (ushort*)carve((size_t)CK_*C_*2);
  ushort* Wv1b  = (ushort*)carve((size_t)C_*C_*2);
  ushort* Wv2b  = (ushort*)carve((size_t)C_*C_*2);
  ushort* k1t   = (ushort*)carve((size_t)N_*L_*CK_*2);
  ushort* k2t   = (ushort*)carve((size_t)N_*L_*CK_*2);
  ushort* v1    = (ushort*)carve((size_t)N_*C_*L_*2);
  ushort* v2    = (ushort*)carve((size_t)N_*C_*L_*2);
  float*  S1p   = (float*)carve((size_t)N_*32*L_*4);
  float*  S2p   = (float*)carve((size_t)N_*32*L_*4);
  float*  invS1 = (float*)carve((size_t)N_*L_*4);
  float*  invS2 = (float*)carve((size_t)N_*L_*4);

  convert_x_kernel<<<dim3(L_/64, C_/64, 4), 256, 0, stream>>>(x1, x2, xT1, xT2);
  convert_w_kernel<<<dim3((2*CK_*C_ + 2*C_*C_) / 256), 256, 0, stream>>>(
      Wk1, Wk2, Wv1, Wv2, Wk1b, Wk2b, Wv1b, Wv2b);
  proj_kernel<<<dim3(L_/128, 18, N_), 256, 0, stream>>>(
      xT1, xT2, Wk1b, Wk2b, Wv1b, Wv2b, bk1, bk2, bv1, bv2, k1t, k2t, v1, v2);
  stats_kernel<<<dim3(L_/128, L_/128, N_), 256, 0, stream>>>(k1t, k2t, S1p, S2p);
  reduce_inv_kernel<<<dim3(2*N_*L_/256), 256, 0, stream>>>(S1p, S2p, invS1, invS2);
  cross_attn_r_kernel<<<dim3(L_/64, C_/128, 2*N_), 256, 0, stream>>>(
      k1t, k2t, v1, v2, invS1, invS2, x1, x2, (float*)d_out);
}